// Round 15
// baseline (2509.712 us; speedup 1.0000x reference)
//
#include <hip/hip_runtime.h>

// InverseRecurrentLayer v14b — v14 with the compile fix (stray `q[i].f ? :` artifact).
//  (1) epilogue: state stores -> waitvm0 -> per-wave flag -> THEN out NT stores:
//      v11 drained the HBM out-store acks before flagging (vmcnt is FIFO) —
//      ~1us of HBM write latency sat on the producer->consumer chain each step.
//  (2) per-wave producer flags (8 u32/line per block): no end-of-step barrier,
//      a wave flags as soon as ITS 4 state stores ack at MALL.
//  (3) consumer wave w polls producer w's 8 wave-flags (lanes 0-7, 1 load each).
//  Depth-2 ping-pong safety: wave flag >= t+1 => that wave passed the post-stage
//  __syncthreads of step t-1 => all its reads of the to-be-overwritten slot done.

#define TSTEPS 512

typedef __attribute__((ext_vector_type(4))) float f32x4;
typedef __attribute__((ext_vector_type(8))) _Float16 f16x8;
typedef unsigned long long u64;
typedef unsigned int u32;

union pk2 { _Float16 h[2]; u32 u; };
union chunk16 { f32x4 f; u32 d[4]; _Float16 h[8]; };

__device__ __forceinline__ f32x4 mfma16(f16x8 a, f16x8 b, f32x4 c){
  return __builtin_amdgcn_mfma_f32_16x16x32_f16(a, b, c, 0, 0, 0);
}
__device__ __forceinline__ void waitvm0(){ asm volatile("s_waitcnt vmcnt(0)" ::: "memory"); }
__device__ __forceinline__ f32x4 gload_sc1_b128(const void* p){
  f32x4 r; asm volatile("global_load_dwordx4 %0, %1, off sc1" : "=v"(r) : "v"(p) : "memory"); return r;
}
__device__ __forceinline__ void gstore_sc1_b128(void* p, f32x4 d){
  asm volatile("global_store_dwordx4 %0, %1, off sc1" :: "v"(p), "v"(d) : "memory");
}
__device__ __forceinline__ void u32store_mall(u32* p, u32 v){
  __hip_atomic_store(p, v, __ATOMIC_RELAXED, __HIP_MEMORY_SCOPE_AGENT);
}
__device__ __forceinline__ u32 u32load_mall(const u32* p){
  return __hip_atomic_load(p, __ATOMIC_RELAXED, __HIP_MEMORY_SCOPE_AGENT);
}

// ---------------- (1) weight convert ----------------
__global__ void cvt_wr(const float* __restrict__ W, const float* __restrict__ R,
                       _Float16* __restrict__ Wa, _Float16* __restrict__ Wb,
                       _Float16* __restrict__ Rt){
  const int n  = gridDim.x * blockDim.x;
  const int id = blockIdx.x * blockDim.x + threadIdx.x;
  for (int i = id; i < 1024*1024; i += n){
    const float v = W[i];
    Wa[i] = (_Float16)v;                              // Wa[u][k] = W[u][k]  (W^T op)
    const int k = i >> 10, u = i & 1023;
    Wb[u*1024 + k] = (_Float16)v;                     // Wb[u][k] = W[k][u]  (W op)
  }
  for (int i = id; i < 512*1024; i += n){
    const int f = i >> 10, u = i & 1023;
    Rt[u*512 + f] = (_Float16)R[i];                   // Rt[u][f] = R[f][u]
  }
}

// ---------------- (2) h prepass ----------------
__global__ __launch_bounds__(512, 2) void h_prepass(
    const float* __restrict__ inputs, const _Float16* __restrict__ Rt,
    const float* __restrict__ bias, float* __restrict__ out){
  const int t  = blockIdx.x;
  const int w  = threadIdx.x >> 6, l = threadIdx.x & 63;
  const int lr = l & 15, lg = l >> 4;
  const int b0 = (w >> 1) * 16;
  const int c0 = (w & 1) * 512;

  f32x4 acc[32];
  #pragma unroll
  for (int n = 0; n < 32; ++n) acc[n] = (f32x4){0.f,0.f,0.f,0.f};

  for (int kc = 0; kc < 16; ++kc){
    const float* ip = inputs + (size_t)(b0 + lr)*262144 + (size_t)t*512 + kc*32 + lg*8;
    float4 xa = *(const float4*)ip, xb = *(const float4*)(ip + 4);
    f16x8 a;
    a[0]=(_Float16)xa.x; a[1]=(_Float16)xa.y; a[2]=(_Float16)xa.z; a[3]=(_Float16)xa.w;
    a[4]=(_Float16)xb.x; a[5]=(_Float16)xb.y; a[6]=(_Float16)xb.z; a[7]=(_Float16)xb.w;
    const _Float16* rp = Rt + (size_t)(c0 + lr)*512 + kc*32 + lg*8;
    #pragma unroll
    for (int n = 0; n < 32; ++n){
      f16x8 b = *(const f16x8*)(rp + (size_t)n*(16*512));
      acc[n] = mfma16(a, b, acc[n]);
    }
  }
  #pragma unroll
  for (int n = 0; n < 32; ++n){
    const int u = c0 + n*16 + lr;
    const float bu = bias[u];
    #pragma unroll
    for (int j = 0; j < 4; ++j)
      out[(size_t)t*65536 + (size_t)(b0 + lg*4 + j)*1024 + u] = acc[n][j] + bu;
  }
}

// ---------------- (3) scan ----------------
__global__ __launch_bounds__(512, 2) void irl_scan(
    const _Float16* __restrict__ Wa, const _Float16* __restrict__ Wb,
    const float* __restrict__ x0, float* __restrict__ out,
    unsigned short* __restrict__ st, unsigned* __restrict__ flags)
{
  __shared__ char alds[16 * 2048];     // row-group state [16 rows][1024 k], swizzled

  const int tid = threadIdx.x;
  const int w   = tid >> 6;            // wave = n-tile owner AND producer-w stager
  const int l   = tid & 63;
  const int lr  = l & 15;
  const int lg  = l >> 4;
  const int cblk = blockIdx.x & 7;     // col-split (producer id in group)
  const int grp  = blockIdx.x >> 3;    // row-group
  const int col0 = cblk << 7;          // 128 cols per block
  const int r0   = grp << 4;           // 16 rows per group
  const int u    = col0 + w*16 + lr;
  u32* myflags   = flags + (((grp << 3) + cblk) << 4);   // this block's 8 wave-flags
  const u32* pfl = flags + (((grp << 3) + w) << 4);      // producer w's 8 wave-flags

  // ---- state[0] <- x0 : 16 rows x 16 chunks of 16B ----
  if (tid < 256){
    const int row = tid >> 4, ch = tid & 15;
    chunk16 c;
    #pragma unroll
    for (int j = 0; j < 8; ++j) c.h[j] = (_Float16)x0[col0 + ch*8 + j];
    gstore_sc1_b128((char*)st + (size_t)(r0 + row)*2048 + col0*2 + ch*16, c.f);
  }
  waitvm0();
  __syncthreads();
  if (tid < 8) u32store_mall(myflags + tid, 1u);

  unsigned cur = 0;
  int pp = -1;
  f16x8 wf[32];                        // current phase, full K=1024 (128 VGPR)
  for (int t = 0; t < TSTEPS; ++t){
    const int ph = (t >> 6) & 1;       // 1 -> W (Wb), 0 -> W^T (Wa)
    if (ph != pp){
      pp = ph;
      const _Float16* Wsel = ph ? Wb : Wa;
      #pragma unroll
      for (int i = 0; i < 32; ++i)
        wf[i] = *(const f16x8*)(Wsel + (size_t)u*1024 + i*32 + lg*8);
    }

    // h prefetch (own prepass slice; plain cached loads, drained at stage waitvm0)
    float hv[4];
    #pragma unroll
    for (int j = 0; j < 4; ++j)
      hv[j] = out[(size_t)t*65536 + (size_t)(r0 + lg*4 + j)*1024 + u];

    // ---- gate: wave w waits for producer w's 8 wave-flags (lanes 0-7) ----
    {
      const unsigned gen = (unsigned)(t + 1);
      for (;;){
        unsigned v = gen;
        if (l < 8) v = u32load_mall(pfl + l);
        if (__all((int)(v >= gen))) break;
        __builtin_amdgcn_s_sleep(1);
      }
    }
    asm volatile("" ::: "memory");

    // ---- stage producer w's 16x128 slice: 4 batched sc1 16B loads, one waitcnt ----
    const char* base = (const char*)st + ((size_t)cur << 17)
                     + (size_t)r0*2048 + w*256 + lr*16;
    f32x4 q[4];
    #pragma unroll
    for (int i = 0; i < 4; ++i)
      q[i] = gload_sc1_b128(base + (size_t)(i*4 + lg)*2048);
    waitvm0();
    __syncthreads();                   // prev-step MFMA reads of alds complete
    #pragma unroll
    for (int i = 0; i < 4; ++i){
      const int row = i*4 + lg, c = w*256 + lr*16;
      *(f32x4*)(alds + row*2048 + (c ^ ((row & 7) << 4))) = q[i];
    }
    __syncthreads();

    // ---- recurrent GEMM: 32 MFMAs, 2 chains ----
    f32x4 ac0 = {0.f,0.f,0.f,0.f}, ac1 = ac0;
    #pragma unroll
    for (int i = 0; i < 32; i += 2){
      f16x8 a0 = *(const f16x8*)(alds + lr*2048 + ((i*64 + lg*16) ^ ((lr & 7) << 4)));
      f16x8 a1 = *(const f16x8*)(alds + lr*2048 + (((i+1)*64 + lg*16) ^ ((lr & 7) << 4)));
      ac0 = mfma16(a0, wf[i], ac0);
      ac1 = mfma16(a1, wf[i+1], ac1);
    }
    const f32x4 acc = ac0 + ac1;

    // ---- epilogue, reordered: tanh+pack ALL rows -> state stores -> drain ->
    //      per-wave flag -> THEN out NT stores (HBM acks off the critical path).
    char* nbB = (char*)st + ((size_t)(cur ^ 1u) << 17);
    float vv[4];
    chunk16 cst[4];
    #pragma unroll
    for (int j = 0; j < 4; ++j){
      const float v = tanhf(acc[j] + hv[j]);
      vv[j] = v;
      pk2 me; me.h[0] = (_Float16)v; me.h[1] = (_Float16)0.f;
      const u32 two = (me.u & 0xffffu) | ((u32)__shfl_xor((int)me.u, 1) << 16);
      const u32 lo4 = two, hi4 = (u32)__shfl_xor((int)two, 2);
      cst[j].d[0] = lo4;
      cst[j].d[1] = hi4;
      cst[j].d[2] = (u32)__shfl_xor((int)lo4, 4);
      cst[j].d[3] = (u32)__shfl_xor((int)hi4, 4);
    }
    if (!(lr & 7)){
      #pragma unroll
      for (int j = 0; j < 4; ++j)
        gstore_sc1_b128(nbB + (size_t)(r0 + lg*4 + j)*2048 + (size_t)(u & ~7)*2, cst[j].f);
    }
    waitvm0();                         // drains ONLY the 4 state stores (+ spent loads)
    if (l == 0)
      u32store_mall(myflags + w, (unsigned)(t + 2));
    #pragma unroll
    for (int j = 0; j < 4; ++j)
      __builtin_nontemporal_store(vv[j],
        out + (size_t)t*65536 + (size_t)(r0 + lg*4 + j)*1024 + u);

    cur ^= 1u;
  }
}

extern "C" void kernel_launch(void* const* d_in, const int* in_sizes, int n_in,
                              void* d_out, int out_size, void* d_ws, size_t ws_size,
                              hipStream_t stream){
  (void)in_sizes; (void)n_in; (void)out_size; (void)ws_size;
  const float* inputs = (const float*)d_in[0];   // [64,512,512] f32
  const float* R      = (const float*)d_in[1];   // [512,1024]  f32
  const float* W      = (const float*)d_in[2];   // [1024,1024] f32
  const float* bias   = (const float*)d_in[3];   // [1024]      f32
  const float* x0     = (const float*)d_in[4];   // [1024]      f32
  float* out = (float*)d_out;                    // [512,64,1024] f32 (h, then states)

  char* ws = (char*)d_ws;
  unsigned* flags     = (unsigned*)ws;                    // 4 KB (32 x 8 wave-flags)
  unsigned short* st  = (unsigned short*)(ws + 4096);     // 2 x 64x1024 fp16 (256 KB)
  _Float16* Rt = (_Float16*)(ws + (512<<10));             // 1 MB  @ 0.5 MB
  _Float16* Wa = (_Float16*)(ws + (2u<<20));              // 2 MB  @ 2 MB
  _Float16* Wb = (_Float16*)(ws + (4u<<20));              // 2 MB  @ 4 MB

  (void)hipMemsetAsync(flags, 0, 4096, stream);
  hipLaunchKernelGGL(cvt_wr,    dim3(1024), dim3(256), 0, stream, W, R, Wa, Wb, Rt);
  hipLaunchKernelGGL(h_prepass, dim3(512),  dim3(512), 0, stream, inputs, Rt, bias, out);
  hipLaunchKernelGGL(irl_scan,  dim3(32),   dim3(512), 0, stream, Wa, Wb, x0, out, st, flags);
}